// Round 14
// baseline (79.549 us; speedup 1.0000x reference)
//
#include <hip/hip_runtime.h>
#include <hip/hip_bf16.h>
#include <math.h>

#define NB 8
#define NC 512
#define NN 1024      // H*W
#define NHEADS 8
#define EPSV 1e-5f
#define SC2F 0.06376351307f   // 512^-0.5 * log2(e)

typedef __attribute__((ext_vector_type(8))) short bf16x8;
typedef __attribute__((ext_vector_type(4))) short bf16x4;
typedef __attribute__((ext_vector_type(4))) float f32x4;
typedef __attribute__((ext_vector_type(16))) float f32x16;

#define MFMA16(a,b,c) __builtin_amdgcn_mfma_f32_16x16x32_bf16(a,b,c,0,0,0)
#define MFMA32(a,b,c) __builtin_amdgcn_mfma_f32_32x32x16_bf16(a,b,c,0,0,0)

static __device__ __forceinline__ short f2bf(float f) {
    __hip_bfloat16 h = __float2bfloat16(f);
    return *reinterpret_cast<short*>(&h);
}

static __device__ __forceinline__ unsigned cvt_pk_bf16(float lo, float hi) {
    unsigned r;
    asm("v_cvt_pk_bf16_f32 %0, %1, %2" : "=v"(r) : "v"(lo), "v"(hi));
    return r;
}

static __device__ __forceinline__ void gload16(const void* g, void* l) {
    __builtin_amdgcn_global_load_lds((const __attribute__((address_space(1))) void*)g,
                                     (__attribute__((address_space(3))) void*)l, 16, 0, 0);
}

// ws layout (float offsets):
#define WS_PART_SUM 0            // 512
#define WS_PART_SQ  1024         // 512
#define WS_XNT   4096                    // bf16 [8][1024][512]
#define WS_QT    (WS_XNT  + 2097152)     // bf16 [64][1024][64]  (d fragment-permuted, pre-scaled)
#define WS_KT    (WS_QT   + 2097152)     // bf16 [64][1024][64]  (d fragment-permuted)
#define WS_V     (WS_KT   + 2097152)     // bf16 [64][64][1024]  (keys permuted within 64-groups)
#define WS_VALST (WS_V    + 2097152)     // bf16 [8][1024][512]
#define WS_WQB   (WS_VALST+ 2097152)     // bf16 [1536][512]
#define WS_WPB   (WS_WQB  + 393216)      // bf16 [512][512]

// ---------------- prep: batch-stat partials + weight convert (fused, 512 blocks) ----------------
__global__ __launch_bounds__(256) void prep_kernel(const float* __restrict__ x,
                                                   const float* __restrict__ wq,
                                                   const float* __restrict__ wp,
                                                   float* __restrict__ ws) {
    int blk = blockIdx.x;
    int b = blk >> 6;
    int s = blk & 63;
    const float* xb = x + (size_t)b * (NC * NN) + (size_t)s * 8192;
    float sum = 0.f, sq = 0.f;
    for (int i = threadIdx.x; i < 2048; i += 256) {
        float4 v = ((const float4*)xb)[i];
        sum += v.x + v.y + v.z + v.w;
        sq  += v.x*v.x + v.y*v.y + v.z*v.z + v.w*v.w;
    }
    #pragma unroll
    for (int off = 32; off; off >>= 1) {
        sum += __shfl_down(sum, off);
        sq  += __shfl_down(sq,  off);
    }
    __shared__ float s1[4], s2[4];
    int wave = threadIdx.x >> 6, lane = threadIdx.x & 63;
    if (lane == 0) { s1[wave] = sum; s2[wave] = sq; }

    // weight convert: 2 float4 per thread, 512*256*2 = 262144 = exact cover
    #pragma unroll
    for (int r = 0; r < 2; r++) {
        int i = blk * 512 + threadIdx.x * 2 + r;
        const float* src;
        __hip_bfloat16* d;
        if (i < 196608) { src = wq; d = (__hip_bfloat16*)(ws + WS_WQB); }
        else            { src = wp; d = (__hip_bfloat16*)(ws + WS_WPB); i -= 196608; }
        float4 v = ((const float4*)src)[i];
        bf16x4 w;
        w[0] = f2bf(v.x); w[1] = f2bf(v.y); w[2] = f2bf(v.z); w[3] = f2bf(v.w);
        *(bf16x4*)(d + (size_t)i*4) = w;
    }

    __syncthreads();
    if (threadIdx.x == 0) {
        float a = 0.f, c2 = 0.f;
        #pragma unroll
        for (int w = 0; w < 4; w++) { a += s1[w]; c2 += s2[w]; }
        ws[WS_PART_SUM + b*64 + s] = a;
        ws[WS_PART_SQ  + b*64 + s] = c2;
    }
}

// ---------------- normalize + transpose -> xnT[b][n][c] bf16 (stats finalized inline) ----------------
__global__ __launch_bounds__(256) void normalize_t(const float* __restrict__ x,
                                                   const float* __restrict__ gamma,
                                                   const float* __restrict__ beta,
                                                   const float* __restrict__ ws,
                                                   __hip_bfloat16* __restrict__ xnT) {
    int nt = blockIdx.x & 15, ct = (blockIdx.x >> 4) & 7, b = blockIdx.x >> 7;
    __shared__ __hip_bfloat16 tb[64][72];
    float s = 0.f, q = 0.f;
    const float4* ps = (const float4*)(ws + WS_PART_SUM + b*64);
    const float4* pq = (const float4*)(ws + WS_PART_SQ  + b*64);
    #pragma unroll
    for (int i = 0; i < 16; i++) {
        float4 a = ps[i]; s += a.x + a.y + a.z + a.w;
        float4 c = pq[i]; q += c.x + c.y + c.z + c.w;
    }
    const float inv = 1.f / (float)(NC * NN);
    float mu   = s * inv;
    float var  = q * inv - mu * mu;
    float rstd = rsqrtf(var + EPSV);

    const float* xb = x + ((size_t)b*512 + ct*64)*1024 + nt*64;
    int t = threadIdx.x;
    int cl = t >> 4, n4 = (t & 15) * 4;
    #pragma unroll
    for (int i = 0; i < 4; i++) {
        int c = i*16 + cl;
        float gm = gamma[ct*64 + c];
        float g = gm * rstd;
        float be = beta[ct*64 + c] - mu * g;
        float4 v = *(const float4*)(xb + (size_t)c*1024 + n4);
        tb[n4+0][c] = __float2bfloat16(v.x*g + be);
        tb[n4+1][c] = __float2bfloat16(v.y*g + be);
        tb[n4+2][c] = __float2bfloat16(v.z*g + be);
        tb[n4+3][c] = __float2bfloat16(v.w*g + be);
    }
    __syncthreads();
    #pragma unroll
    for (int i = 0; i < 2; i++) {
        int idx = i*256 + t;
        int n = idx >> 3, c8 = (idx & 7) * 8;
        *(bf16x8*)(xnT + ((size_t)b*1024 + nt*64 + n)*512 + ct*64 + c8) =
            *(const bf16x8*)&tb[n][c8];
    }
}

// ---------------- MFMA bf16 GEMM (round-8 form): Y[o][n] = sum_c A[o][c] * BxT[n][c] ----------------
template<int OT, int MODE>
__global__ __launch_bounds__(256) void gemm_mfma(const __hip_bfloat16* __restrict__ Aw,
                                                 const __hip_bfloat16* __restrict__ Bx,
                                                 const float* __restrict__ bias,
                                                 float* __restrict__ Yout,
                                                 __hip_bfloat16* __restrict__ QTx,
                                                 __hip_bfloat16* __restrict__ KTx,
                                                 __hip_bfloat16* __restrict__ Vx) {
    __shared__ __align__(16) __hip_bfloat16 lds_raw[17408];
    // batch-affinity XCD swizzle: all blocks of batch bb land on XCD bb
    const int bx = blockIdx.x;
    const int swz = (bx & 7) * (OT * 8) + (bx >> 3);
    const int nt = swz & 7;
    const int ot = (swz >> 3) % OT;
    const int bb = swz / (8 * OT);
    const int o0 = ot * 128, n0 = nt * 128;

    const int t = threadIdx.x, wv = t >> 6, l = t & 63;
    const int lr = l & 31, lh = l >> 5;
    const int wr = wv >> 1, wc = wv & 1;

    const __hip_bfloat16* Ag = Aw + (size_t)o0 * 512;
    const __hip_bfloat16* Bg = Bx + ((size_t)bb * 1024 + n0) * 512;
    __hip_bfloat16* Ab = lds_raw;
    __hip_bfloat16* Bb = lds_raw + 128*64;

    f32x16 acc[2][2];
    #pragma unroll
    for (int a1 = 0; a1 < 2; a1++)
        #pragma unroll
        for (int a2 = 0; a2 < 2; a2++)
            #pragma unroll
            for (int r = 0; r < 16; r++) acc[a1][a2][r] = 0.f;

    const int srow = wv*8 + (l >> 3);
    const int sblk = (l & 7) ^ (l >> 3);

    for (int k0 = 0; k0 < 512; k0 += 64) {
        __syncthreads();
        #pragma unroll
        for (int c = 0; c < 4; c++) {
            int row = c*32 + srow;
            gload16(Ag + (size_t)row*512 + k0 + sblk*8, Ab + (c*32 + wv*8)*64);
            gload16(Bg + (size_t)row*512 + k0 + sblk*8, Bb + (c*32 + wv*8)*64);
        }
        __syncthreads();
        #pragma unroll
        for (int ks = 0; ks < 4; ks++) {
            bf16x8 af[2], bfr[2];
            #pragma unroll
            for (int mi = 0; mi < 2; mi++) {
                int row = wr*64 + mi*32 + lr;
                af[mi] = *(const bf16x8*)(Ab + row*64 + (((ks*2 + lh) ^ (row & 7)) * 8));
            }
            #pragma unroll
            for (int ni = 0; ni < 2; ni++) {
                int row = wc*64 + ni*32 + lr;
                bfr[ni] = *(const bf16x8*)(Bb + row*64 + (((ks*2 + lh) ^ (row & 7)) * 8));
            }
            acc[0][0] = MFMA32(af[0], bfr[0], acc[0][0]);
            acc[0][1] = MFMA32(af[0], bfr[1], acc[0][1]);
            acc[1][0] = MFMA32(af[1], bfr[0], acc[1][0]);
            acc[1][1] = MFMA32(af[1], bfr[1], acc[1][1]);
        }
    }

    // C/D map (verified m74/m101): col = lr, row = (r&3) + 8*(r>>2) + 4*lh
    if (MODE == 0) {
        #pragma unroll
        for (int mi = 0; mi < 2; mi++)
            #pragma unroll
            for (int q = 0; q < 4; q++) {
                int obase = o0 + wr*64 + mi*32 + 8*q + 4*lh;
                float4 bv = *(const float4*)(bias + obase);
                #pragma unroll
                for (int ni = 0; ni < 2; ni++) {
                    int nn = n0 + wc*64 + ni*32 + lr;
                    #pragma unroll
                    for (int j = 0; j < 4; j++)
                        Yout[((size_t)bb*512 + obase + j)*1024 + nn] = acc[mi][ni][q*4+j] + bv[j];
                }
            }
    } else {
        int sec = o0 >> 9;                 // 0=Q 1=K 2=V
        if (sec == 2) {
            int od0 = o0 & 511;
            // permute keys within 64-groups: m=32ks+16u+4g+j -> p=32ks+8g+4u+j
            int mperm = ((lr & 12) << 1) + ((lr & 16) >> 2) + (lr & 3);
            #pragma unroll
            for (int mi = 0; mi < 2; mi++)
                #pragma unroll
                for (int q = 0; q < 4; q++) {
                    int ob = wr*64 + mi*32 + 8*q + 4*lh;
                    float4 bv = *(const float4*)(bias + o0 + ob);
                    #pragma unroll
                    for (int j = 0; j < 4; j++) {
                        int ol = od0 + ob + j;
                        int h = ol >> 6, d = ol & 63;
                        __hip_bfloat16* dst = Vx + ((size_t)((bb<<3) + h)*64 + d)*1024;
                        #pragma unroll
                        for (int ni = 0; ni < 2; ni++) {
                            int nn = n0 + wc*64 + ni*32 + mperm;
                            dst[nn] = __float2bfloat16(acc[mi][ni][q*4+j] + bv[j]);
                        }
                    }
                }
        } else {
            // Q gets pre-scaled by 512^-0.5*log2(e) so attention skips the scale mul
            const float qs = (sec == 0) ? SC2F : 1.0f;
            __syncthreads();
            __hip_bfloat16* tb = lds_raw;  // [128][136]
            #pragma unroll
            for (int mi = 0; mi < 2; mi++)
                #pragma unroll
                for (int q = 0; q < 4; q++) {
                    int ob = wr*64 + mi*32 + 8*q + 4*lh;
                    float4 bv = *(const float4*)(bias + o0 + ob);
                    #pragma unroll
                    for (int ni = 0; ni < 2; ni++) {
                        int nn = wc*64 + ni*32 + lr;
                        bf16x4 w;
                        #pragma unroll
                        for (int j = 0; j < 4; j++) w[j] = f2bf((acc[mi][ni][q*4+j] + bv[j]) * qs);
                        *(bf16x4*)&tb[(size_t)nn*136 + ob] = w;
                    }
                }
            __syncthreads();
            __hip_bfloat16* dst0 = (sec == 0) ? QTx : KTx;
            int h0 = (o0 & 511) >> 6;
            // d-permuted store: position-group slot holds logical d {32hf+4g+j, 32hf+16+4g+j}
            #pragma unroll
            for (int i = 0; i < 8; i++) {
                int idx = i*256 + t;
                int n = idx >> 4, rem = idx & 15;
                int hh = rem >> 3, slot = rem & 7;
                int hf32 = (slot & 4) << 3;
                int g4   = (slot & 3) << 2;
                bf16x4 lo = *(const bf16x4*)&tb[(size_t)n*136 + hh*64 + hf32 + g4];
                bf16x4 hi = *(const bf16x4*)&tb[(size_t)n*136 + hh*64 + hf32 + 16 + g4];
                bf16x8 w;
                w[0]=lo[0]; w[1]=lo[1]; w[2]=lo[2]; w[3]=lo[3];
                w[4]=hi[0]; w[5]=hi[1]; w[6]=hi[2]; w[7]=hi[3];
                *(bf16x8*)(dst0 + ((size_t)((bb<<3) + h0 + hh)*1024 + n0 + n)*64 + slot*8) = w;
            }
        }
    }
}

// ---------------- MFMA flash attention: 4 waves x 32 queries, shared K/V fragment reads ----------------
// Each ds_read kf/vf now feeds TWO MFMAs (two 16-query groups per wave):
// per-CU LDS-read instructions per chunk halve vs the 16-query/wave version.
__global__ __launch_bounds__(256) void attn_mfma(const __hip_bfloat16* __restrict__ QT,
                                                 const __hip_bfloat16* __restrict__ KT,
                                                 const __hip_bfloat16* __restrict__ Vb,
                                                 __hip_bfloat16* __restrict__ valsT) {
    // XCD-grouped decomposition: all 8 q-tiles of one (b,h) share an XCD
    const int bh = ((blockIdx.x & 7) << 3) | ((blockIdx.x >> 3) & 7);
    const int qt = blockIdx.x >> 6;            // 0..7 (128 queries each)
    const int t = threadIdx.x;                 // 0..255
    const int wv = t >> 6, lane = t & 63;
    const int g = lane >> 4, li = lane & 15;

    const __hip_bfloat16* QTg = QT + (size_t)bh * NN * 64;
    const __hip_bfloat16* KTg = KT + (size_t)bh * NN * 64;
    const __hip_bfloat16* Vg  = Vb + (size_t)bh * 64 * NN;

    __shared__ __align__(16) __hip_bfloat16 k_ls[3*4096];
    __shared__ __align__(16) __hip_bfloat16 v_ls[3*4096];

    const int nq0 = qt*128 + wv*32;            // wave owns queries nq0..nq0+31 (2 groups of 16)

    // Q fragments per group: pre-scaled + fragment-permuted in global
    bf16x8 qf[2][2];
    #pragma unroll
    for (int go = 0; go < 2; go++) {
        const __hip_bfloat16* qp = QTg + (size_t)(nq0 + go*16 + li) * 64;
        qf[go][0] = *(const bf16x8*)(qp + 8*g);
        qf[go][1] = *(const bf16x8*)(qp + 32 + 8*g);
    }

    // all-ones B fragment (bf16 1.0) for the l row-sum MFMA
    bf16x8 onesf;
    #pragma unroll
    for (int j = 0; j < 8; j++) onesf[j] = (short)0x3F80;

    float m_run[2] = {0.0f, 0.0f};
    f32x4 o_acc[2][4], o_l[2];
    #pragma unroll
    for (int go = 0; go < 2; go++) {
        #pragma unroll
        for (int dt = 0; dt < 4; dt++) { o_acc[go][dt][0]=0.f; o_acc[go][dt][1]=0.f; o_acc[go][dt][2]=0.f; o_acc[go][dt][3]=0.f; }
        o_l[go][0]=0.f; o_l[go][1]=0.f; o_l[go][2]=0.f; o_l[go][3]=0.f;
    }

    // 2 K-loads + 2 V-loads per thread per chunk (256 threads x 2 x 16B = 8KB each)
    auto STAGE = [&](int buf, int ck) {
        const int mc0 = ck * 64;
        #pragma unroll
        for (int p = 0; p < 2; p++) {
            int idx = t + p*256;
            int row = idx >> 3, sl = idx & 7;
            int sk = sl ^ (row & 7);
            gload16(KTg + (size_t)(mc0+row)*64 + sk*8, k_ls + buf*4096 + idx*8);
            gload16(Vg + (size_t)row*NN + mc0 + sk*8, v_ls + buf*4096 + idx*8);
        }
    };

    // 2-deep prefetch prologue: chunks 0,1 in flight (8 loads); drain chunk 0 -> vmcnt(4)
    STAGE(0, 0);
    STAGE(1, 1);
    asm volatile("s_waitcnt vmcnt(4)" ::: "memory");
    __builtin_amdgcn_s_barrier();

    for (int ck = 0; ck < 16; ck++) {
        const int cb = ck % 3;
        if (ck < 14) STAGE((ck + 2) % 3, ck + 2);

        const __hip_bfloat16* kb = k_ls + cb*4096;
        const __hip_bfloat16* vb = v_ls + cb*4096;

        // QK^T (S^T) for both groups off one kf read; C-init = -m_run folds max-sub.
        f32x4 s_acc[2][4];
        f32x4 cini0, cini1;
        cini0[0] = -m_run[0]; cini0[1] = -m_run[0]; cini0[2] = -m_run[0]; cini0[3] = -m_run[0];
        cini1[0] = -m_run[1]; cini1[1] = -m_run[1]; cini1[2] = -m_run[1]; cini1[3] = -m_run[1];
        __builtin_amdgcn_s_setprio(1);
        #pragma unroll
        for (int mt = 0; mt < 4; mt++) {
            f32x4 c0 = cini0, c1 = cini1;
            #pragma unroll
            for (int hf = 0; hf < 2; hf++) {
                int row = mt*16 + li;
                int sl = ((hf<<2) + g) ^ (li & 7);
                bf16x8 kf = *(const bf16x8*)(kb + row*64 + sl*8);
                c0 = MFMA16(kf, qf[0][hf], c0);
                c1 = MFMA16(kf, qf[1][hf], c1);
            }
            s_acc[0][mt] = c0;
            s_acc[1][mt] = c1;
        }
        __builtin_amdgcn_s_setprio(0);

        // row max per group (relative to m_run), then cross-lane
        float cmax[2];
        #pragma unroll
        for (int go = 0; go < 2; go++) {
            float cm = fmaxf(s_acc[go][0][0], s_acc[go][0][1]);
            cm = fmaxf(fmaxf(cm, s_acc[go][0][2]), s_acc[go][0][3]);
            cm = fmaxf(fmaxf(cm, s_acc[go][1][0]), s_acc[go][1][1]);
            cm = fmaxf(fmaxf(cm, s_acc[go][1][2]), s_acc[go][1][3]);
            cm = fmaxf(fmaxf(cm, s_acc[go][2][0]), s_acc[go][2][1]);
            cm = fmaxf(fmaxf(cm, s_acc[go][2][2]), s_acc[go][2][3]);
            cm = fmaxf(fmaxf(cm, s_acc[go][3][0]), s_acc[go][3][1]);
            cm = fmaxf(fmaxf(cm, s_acc[go][3][2]), s_acc[go][3][3]);
            cm = fmaxf(cm, __shfl_xor(cm, 16));
            cm = fmaxf(cm, __shfl_xor(cm, 32));
            cmax[go] = cm;
        }

        if (ck == 0) {
            // force-set running max (accumulators are zero)
            #pragma unroll
            for (int go = 0; go < 2; go++) {
                #pragma unroll
                for (int mt = 0; mt < 4; mt++) {
                    s_acc[go][mt][0] -= cmax[go]; s_acc[go][mt][1] -= cmax[go];
                    s_acc[go][mt][2] -= cmax[go]; s_acc[go][mt][3] -= cmax[go];
                }
                m_run[go] = cmax[go];
            }
        } else if (!__all(cmax[0] <= 8.0f && cmax[1] <= 8.0f)) {  // defer-max (T13)
            #pragma unroll
            for (int go = 0; go < 2; go++) {
                float d = fmaxf(cmax[go], 0.0f);
                float resc = __builtin_amdgcn_exp2f(-d);
                f32x4 rv;
                #pragma unroll
                for (int r = 0; r < 4; r++) rv[r] = __shfl(resc, 4*g + r);
                #pragma unroll
                for (int dt = 0; dt < 4; dt++) {
                    o_acc[go][dt][0]*=rv[0]; o_acc[go][dt][1]*=rv[1];
                    o_acc[go][dt][2]*=rv[2]; o_acc[go][dt][3]*=rv[3];
                }
                o_l[go][0]*=rv[0]; o_l[go][1]*=rv[1]; o_l[go][2]*=rv[2]; o_l[go][3]*=rv[3];
                #pragma unroll
                for (int mt = 0; mt < 4; mt++) {
                    s_acc[go][mt][0] -= d; s_acc[go][mt][1] -= d;
                    s_acc[go][mt][2] -= d; s_acc[go][mt][3] -= d;
                }
                m_run[go] += d;
            }
        }

        // P = exp2(s_acc) (already max-relative), packed via v_cvt_pk_bf16_f32
        bf16x8 pf[2][2];
        #pragma unroll
        for (int go = 0; go < 2; go++) {
            #pragma unroll
            for (int ks = 0; ks < 2; ks++) {
                union { bf16x8 v; unsigned u[4]; } pk;
                #pragma unroll
                for (int d4 = 0; d4 < 4; d4++) {
                    const int i0 = 8*ks + 2*d4, i1 = i0 + 1;
                    float e0 = __builtin_amdgcn_exp2f(s_acc[go][i0>>2][i0&3]);
                    float e1 = __builtin_amdgcn_exp2f(s_acc[go][i1>>2][i1&3]);
                    pk.u[d4] = cvt_pk_bf16(e0, e1);
                }
                pf[go][ks] = pk.v;
            }
        }

        // PV + l row-sum: one vf read feeds both groups
        __builtin_amdgcn_s_setprio(1);
        #pragma unroll
        for (int dt = 0; dt < 4; dt++) {
            #pragma unroll
            for (int ks = 0; ks < 2; ks++) {
                int row = dt*16 + li;
                int sl = ((ks<<2) + g) ^ (li & 7);
                bf16x8 vf = *(const bf16x8*)(vb + row*64 + sl*8);
                o_acc[0][dt] = MFMA16(pf[0][ks], vf, o_acc[0][dt]);
                o_acc[1][dt] = MFMA16(pf[1][ks], vf, o_acc[1][dt]);
            }
        }
        #pragma unroll
        for (int go = 0; go < 2; go++) {
            o_l[go] = MFMA16(pf[go][0], onesf, o_l[go]);
            o_l[go] = MFMA16(pf[go][1], onesf, o_l[go]);
        }
        __builtin_amdgcn_s_setprio(0);

        // counted vmcnt (T4): drain chunk ck+1's 4 loads; leave this iter's 4 in flight
        if (ck < 14) asm volatile("s_waitcnt vmcnt(4)" ::: "memory");
        else         asm volatile("s_waitcnt vmcnt(0)" ::: "memory");
        __builtin_amdgcn_s_barrier();
    }

    // epilogue: out = o_acc / o_l per group (row r = query nq0+go*16+4g+r)
    const int bI = bh >> 3, hI = bh & 7;
    __hip_bfloat16* vt = valsT + (size_t)bI*1024*512 + hI*64;
    #pragma unroll
    for (int go = 0; go < 2; go++) {
        f32x4 lv;
        #pragma unroll
        for (int r = 0; r < 4; r++) lv[r] = 1.0f / o_l[go][r];
        #pragma unroll
        for (int dt = 0; dt < 4; dt++)
            #pragma unroll
            for (int r = 0; r < 4; r++)
                vt[(size_t)(nq0 + go*16 + 4*g + r)*512 + dt*16 + li] =
                    __float2bfloat16(o_acc[go][dt][r]*lv[r]);
    }
}

extern "C" void kernel_launch(void* const* d_in, const int* in_sizes, int n_in,
                              void* d_out, int out_size, void* d_ws, size_t ws_size,
                              hipStream_t stream) {
    const float* x      = (const float*)d_in[0];
    const float* gamma  = (const float*)d_in[1];
    const float* beta   = (const float*)d_in[2];
    const float* w_qkv  = (const float*)d_in[3];
    const float* b_qkv  = (const float*)d_in[4];
    const float* w_proj = (const float*)d_in[5];
    const float* b_proj = (const float*)d_in[6];
    float* ws   = (float*)d_ws;
    float* out  = (float*)d_out;
    __hip_bfloat16* xnT   = (__hip_bfloat16*)(ws + WS_XNT);
    __hip_bfloat16* QT    = (__hip_bfloat16*)(ws + WS_QT);
    __hip_bfloat16* KT    = (__hip_bfloat16*)(ws + WS_KT);
    __hip_bfloat16* Vx    = (__hip_bfloat16*)(ws + WS_V);
    __hip_bfloat16* valsT = (__hip_bfloat16*)(ws + WS_VALST);
    __hip_bfloat16* wqb   = (__hip_bfloat16*)(ws + WS_WQB);
    __hip_bfloat16* wpb   = (__hip_bfloat16*)(ws + WS_WPB);

    prep_kernel<<<dim3(512), dim3(256), 0, stream>>>(x, w_qkv, w_proj, ws);
    normalize_t<<<dim3(1024), dim3(256), 0, stream>>>(x, gamma, beta, ws, xnT);
    gemm_mfma<12, 1><<<dim3(768), dim3(256), 0, stream>>>(wqb, xnT, b_qkv,
                                                          nullptr, QT, KT, Vx);
    attn_mfma<<<dim3(512), dim3(256), 0, stream>>>(QT, KT, Vx, valsT);
    gemm_mfma<4, 0><<<dim3(256), dim3(256), 0, stream>>>(wpb, valsT, b_proj,
                                                         out, nullptr, nullptr, nullptr);
}

// Round 15
// 71.675 us; speedup vs baseline: 1.1099x; 1.1099x over previous
//
#include <hip/hip_runtime.h>
#include <hip/hip_bf16.h>
#include <math.h>

#define NB 8
#define NC 512
#define NN 1024      // H*W
#define NHEADS 8
#define EPSV 1e-5f
#define SC2F 0.06376351307f   // 512^-0.5 * log2(e)

typedef __attribute__((ext_vector_type(8))) short bf16x8;
typedef __attribute__((ext_vector_type(4))) short bf16x4;
typedef __attribute__((ext_vector_type(4))) float f32x4;
typedef __attribute__((ext_vector_type(16))) float f32x16;

#define MFMA16(a,b,c) __builtin_amdgcn_mfma_f32_16x16x32_bf16(a,b,c,0,0,0)
#define MFMA32(a,b,c) __builtin_amdgcn_mfma_f32_32x32x16_bf16(a,b,c,0,0,0)

static __device__ __forceinline__ short f2bf(float f) {
    __hip_bfloat16 h = __float2bfloat16(f);
    return *reinterpret_cast<short*>(&h);
}

static __device__ __forceinline__ unsigned cvt_pk_bf16(float lo, float hi) {
    unsigned r;
    asm("v_cvt_pk_bf16_f32 %0, %1, %2" : "=v"(r) : "v"(lo), "v"(hi));
    return r;
}

static __device__ __forceinline__ void gload16(const void* g, void* l) {
    __builtin_amdgcn_global_load_lds((const __attribute__((address_space(1))) void*)g,
                                     (__attribute__((address_space(3))) void*)l, 16, 0, 0);
}

// ws layout (float offsets):
#define WS_PART_SUM 0            // 512
#define WS_PART_SQ  1024         // 512
#define WS_XNT   4096                    // bf16 [8][1024][512]
#define WS_QT    (WS_XNT  + 2097152)     // bf16 [64][1024][64]  (d fragment-permuted, pre-scaled)
#define WS_KT    (WS_QT   + 2097152)     // bf16 [64][1024][64]  (d fragment-permuted)
#define WS_V     (WS_KT   + 2097152)     // bf16 [64][64][1024]  (keys permuted within 64-groups)
#define WS_VALST (WS_V    + 2097152)     // bf16 [8][1024][512]
#define WS_WQB   (WS_VALST+ 2097152)     // bf16 [1536][512]
#define WS_WPB   (WS_WQB  + 393216)      // bf16 [512][512]

// ---------------- prep: batch-stat partials + weight convert (fused, 512 blocks) ----------------
__global__ __launch_bounds__(256) void prep_kernel(const float* __restrict__ x,
                                                   const float* __restrict__ wq,
                                                   const float* __restrict__ wp,
                                                   float* __restrict__ ws) {
    int blk = blockIdx.x;
    int b = blk >> 6;
    int s = blk & 63;
    const float* xb = x + (size_t)b * (NC * NN) + (size_t)s * 8192;
    float sum = 0.f, sq = 0.f;
    for (int i = threadIdx.x; i < 2048; i += 256) {
        float4 v = ((const float4*)xb)[i];
        sum += v.x + v.y + v.z + v.w;
        sq  += v.x*v.x + v.y*v.y + v.z*v.z + v.w*v.w;
    }
    #pragma unroll
    for (int off = 32; off; off >>= 1) {
        sum += __shfl_down(sum, off);
        sq  += __shfl_down(sq,  off);
    }
    __shared__ float s1[4], s2[4];
    int wave = threadIdx.x >> 6, lane = threadIdx.x & 63;
    if (lane == 0) { s1[wave] = sum; s2[wave] = sq; }

    // weight convert: 2 float4 per thread, 512*256*2 = 262144 = exact cover
    #pragma unroll
    for (int r = 0; r < 2; r++) {
        int i = blk * 512 + threadIdx.x * 2 + r;
        const float* src;
        __hip_bfloat16* d;
        if (i < 196608) { src = wq; d = (__hip_bfloat16*)(ws + WS_WQB); }
        else            { src = wp; d = (__hip_bfloat16*)(ws + WS_WPB); i -= 196608; }
        float4 v = ((const float4*)src)[i];
        bf16x4 w;
        w[0] = f2bf(v.x); w[1] = f2bf(v.y); w[2] = f2bf(v.z); w[3] = f2bf(v.w);
        *(bf16x4*)(d + (size_t)i*4) = w;
    }

    __syncthreads();
    if (threadIdx.x == 0) {
        float a = 0.f, c2 = 0.f;
        #pragma unroll
        for (int w = 0; w < 4; w++) { a += s1[w]; c2 += s2[w]; }
        ws[WS_PART_SUM + b*64 + s] = a;
        ws[WS_PART_SQ  + b*64 + s] = c2;
    }
}

// ---------------- normalize + transpose -> xnT[b][n][c] bf16 (stats finalized inline) ----------------
__global__ __launch_bounds__(256) void normalize_t(const float* __restrict__ x,
                                                   const float* __restrict__ gamma,
                                                   const float* __restrict__ beta,
                                                   const float* __restrict__ ws,
                                                   __hip_bfloat16* __restrict__ xnT) {
    int nt = blockIdx.x & 15, ct = (blockIdx.x >> 4) & 7, b = blockIdx.x >> 7;
    __shared__ __hip_bfloat16 tb[64][72];
    float s = 0.f, q = 0.f;
    const float4* ps = (const float4*)(ws + WS_PART_SUM + b*64);
    const float4* pq = (const float4*)(ws + WS_PART_SQ  + b*64);
    #pragma unroll
    for (int i = 0; i < 16; i++) {
        float4 a = ps[i]; s += a.x + a.y + a.z + a.w;
        float4 c = pq[i]; q += c.x + c.y + c.z + c.w;
    }
    const float inv = 1.f / (float)(NC * NN);
    float mu   = s * inv;
    float var  = q * inv - mu * mu;
    float rstd = rsqrtf(var + EPSV);

    const float* xb = x + ((size_t)b*512 + ct*64)*1024 + nt*64;
    int t = threadIdx.x;
    int cl = t >> 4, n4 = (t & 15) * 4;
    #pragma unroll
    for (int i = 0; i < 4; i++) {
        int c = i*16 + cl;
        float gm = gamma[ct*64 + c];
        float g = gm * rstd;
        float be = beta[ct*64 + c] - mu * g;
        float4 v = *(const float4*)(xb + (size_t)c*1024 + n4);
        tb[n4+0][c] = __float2bfloat16(v.x*g + be);
        tb[n4+1][c] = __float2bfloat16(v.y*g + be);
        tb[n4+2][c] = __float2bfloat16(v.z*g + be);
        tb[n4+3][c] = __float2bfloat16(v.w*g + be);
    }
    __syncthreads();
    #pragma unroll
    for (int i = 0; i < 2; i++) {
        int idx = i*256 + t;
        int n = idx >> 3, c8 = (idx & 7) * 8;
        *(bf16x8*)(xnT + ((size_t)b*1024 + nt*64 + n)*512 + ct*64 + c8) =
            *(const bf16x8*)&tb[n][c8];
    }
}

// ---------------- MFMA bf16 QKV GEMM (round-8 form, MODE-1 epilogue only) ----------------
__global__ __launch_bounds__(256) void gemm_qkv(const __hip_bfloat16* __restrict__ Aw,
                                                const __hip_bfloat16* __restrict__ Bx,
                                                const float* __restrict__ bias,
                                                __hip_bfloat16* __restrict__ QTx,
                                                __hip_bfloat16* __restrict__ KTx,
                                                __hip_bfloat16* __restrict__ Vx) {
    const int OT = 12;
    __shared__ __align__(16) __hip_bfloat16 lds_raw[17408];
    const int bx = blockIdx.x;
    const int swz = (bx & 7) * (OT * 8) + (bx >> 3);
    const int nt = swz & 7;
    const int ot = (swz >> 3) % OT;
    const int bb = swz / (8 * OT);
    const int o0 = ot * 128, n0 = nt * 128;

    const int t = threadIdx.x, wv = t >> 6, l = t & 63;
    const int lr = l & 31, lh = l >> 5;
    const int wr = wv >> 1, wc = wv & 1;

    const __hip_bfloat16* Ag = Aw + (size_t)o0 * 512;
    const __hip_bfloat16* Bg = Bx + ((size_t)bb * 1024 + n0) * 512;
    __hip_bfloat16* Ab = lds_raw;
    __hip_bfloat16* Bb = lds_raw + 128*64;

    f32x16 acc[2][2];
    #pragma unroll
    for (int a1 = 0; a1 < 2; a1++)
        #pragma unroll
        for (int a2 = 0; a2 < 2; a2++)
            #pragma unroll
            for (int r = 0; r < 16; r++) acc[a1][a2][r] = 0.f;

    const int srow = wv*8 + (l >> 3);
    const int sblk = (l & 7) ^ (l >> 3);

    for (int k0 = 0; k0 < 512; k0 += 64) {
        __syncthreads();
        #pragma unroll
        for (int c = 0; c < 4; c++) {
            int row = c*32 + srow;
            gload16(Ag + (size_t)row*512 + k0 + sblk*8, Ab + (c*32 + wv*8)*64);
            gload16(Bg + (size_t)row*512 + k0 + sblk*8, Bb + (c*32 + wv*8)*64);
        }
        __syncthreads();
        #pragma unroll
        for (int ks = 0; ks < 4; ks++) {
            bf16x8 af[2], bfr[2];
            #pragma unroll
            for (int mi = 0; mi < 2; mi++) {
                int row = wr*64 + mi*32 + lr;
                af[mi] = *(const bf16x8*)(Ab + row*64 + (((ks*2 + lh) ^ (row & 7)) * 8));
            }
            #pragma unroll
            for (int ni = 0; ni < 2; ni++) {
                int row = wc*64 + ni*32 + lr;
                bfr[ni] = *(const bf16x8*)(Bb + row*64 + (((ks*2 + lh) ^ (row & 7)) * 8));
            }
            acc[0][0] = MFMA32(af[0], bfr[0], acc[0][0]);
            acc[0][1] = MFMA32(af[0], bfr[1], acc[0][1]);
            acc[1][0] = MFMA32(af[1], bfr[0], acc[1][0]);
            acc[1][1] = MFMA32(af[1], bfr[1], acc[1][1]);
        }
    }

    // C/D map (verified m74/m101): col = lr, row = (r&3) + 8*(r>>2) + 4*lh
    int sec = o0 >> 9;                 // 0=Q 1=K 2=V
    if (sec == 2) {
        int od0 = o0 & 511;
        // permute keys within 64-groups: m=32ks+16u+4g+j -> p=32ks+8g+4u+j
        int mperm = ((lr & 12) << 1) + ((lr & 16) >> 2) + (lr & 3);
        #pragma unroll
        for (int mi = 0; mi < 2; mi++)
            #pragma unroll
            for (int q = 0; q < 4; q++) {
                int ob = wr*64 + mi*32 + 8*q + 4*lh;
                float4 bv = *(const float4*)(bias + o0 + ob);
                #pragma unroll
                for (int j = 0; j < 4; j++) {
                    int ol = od0 + ob + j;
                    int h = ol >> 6, d = ol & 63;
                    __hip_bfloat16* dst = Vx + ((size_t)((bb<<3) + h)*64 + d)*1024;
                    #pragma unroll
                    for (int ni = 0; ni < 2; ni++) {
                        int nn = n0 + wc*64 + ni*32 + mperm;
                        dst[nn] = __float2bfloat16(acc[mi][ni][q*4+j] + bv[j]);
                    }
                }
            }
    } else {
        // Q gets pre-scaled by 512^-0.5*log2(e) so attention skips the scale mul
        const float qs = (sec == 0) ? SC2F : 1.0f;
        __syncthreads();
        __hip_bfloat16* tb = lds_raw;  // [128][136]
        #pragma unroll
        for (int mi = 0; mi < 2; mi++)
            #pragma unroll
            for (int q = 0; q < 4; q++) {
                int ob = wr*64 + mi*32 + 8*q + 4*lh;
                float4 bv = *(const float4*)(bias + o0 + ob);
                #pragma unroll
                for (int ni = 0; ni < 2; ni++) {
                    int nn = wc*64 + ni*32 + lr;
                    bf16x4 w;
                    #pragma unroll
                    for (int j = 0; j < 4; j++) w[j] = f2bf((acc[mi][ni][q*4+j] + bv[j]) * qs);
                    *(bf16x4*)&tb[(size_t)nn*136 + ob] = w;
                }
            }
        __syncthreads();
        __hip_bfloat16* dst0 = (sec == 0) ? QTx : KTx;
        int h0 = (o0 & 511) >> 6;
        // d-permuted store: position-group slot holds logical d {32hf+4g+j, 32hf+16+4g+j}
        #pragma unroll
        for (int i = 0; i < 8; i++) {
            int idx = i*256 + t;
            int n = idx >> 4, rem = idx & 15;
            int hh = rem >> 3, slot = rem & 7;
            int hf32 = (slot & 4) << 3;
            int g4   = (slot & 3) << 2;
            bf16x4 lo = *(const bf16x4*)&tb[(size_t)n*136 + hh*64 + hf32 + g4];
            bf16x4 hi = *(const bf16x4*)&tb[(size_t)n*136 + hh*64 + hf32 + 16 + g4];
            bf16x8 w;
            w[0]=lo[0]; w[1]=lo[1]; w[2]=lo[2]; w[3]=lo[3];
            w[4]=hi[0]; w[5]=hi[1]; w[6]=hi[2]; w[7]=hi[3];
            *(bf16x8*)(dst0 + ((size_t)((bb<<3) + h0 + hh)*1024 + n0 + n)*64 + slot*8) = w;
        }
    }
}

// ---------------- proj GEMM: 128o x 64n tiles -> 512 blocks (2 blocks/CU) ----------------
// Wave wv owns rows o0+wv*32 (one 32-row MFMA block), both 32-col halves.
__global__ __launch_bounds__(256) void gemm_proj(const __hip_bfloat16* __restrict__ Aw,
                                                 const __hip_bfloat16* __restrict__ Bx,
                                                 const float* __restrict__ bias,
                                                 float* __restrict__ Yout) {
    __shared__ __align__(16) __hip_bfloat16 lds_raw[12288];  // A 128x64 (16KB) + B 64x64 (8KB)
    const int bx = blockIdx.x;
    const int swz = (bx & 7) * 64 + (bx >> 3);   // batch-affinity XCD swizzle (512%8==0)
    const int nt = swz & 15;
    const int ot = (swz >> 4) & 3;
    const int bb = swz >> 6;
    const int o0 = ot * 128, n0 = nt * 64;

    const int t = threadIdx.x, wv = t >> 6, l = t & 63;
    const int lr = l & 31, lh = l >> 5;

    const __hip_bfloat16* Ag = Aw + (size_t)o0 * 512;
    const __hip_bfloat16* Bg = Bx + ((size_t)bb * 1024 + n0) * 512;
    __hip_bfloat16* Ab = lds_raw;          // [128][64], XOR-swizzled granules
    __hip_bfloat16* Bb = lds_raw + 128*64; // [64][64]

    f32x16 acc[2];
    #pragma unroll
    for (int ni = 0; ni < 2; ni++)
        #pragma unroll
        for (int r = 0; r < 16; r++) acc[ni][r] = 0.f;

    for (int k0 = 0; k0 < 512; k0 += 64) {
        __syncthreads();
        // A: 128 rows x 64k = 1024 granules of 16B -> 4 loads/thread
        #pragma unroll
        for (int p = 0; p < 4; p++) {
            int idx = t + p*256;
            int row = idx >> 3, sl = idx & 7;
            int sk = sl ^ (row & 7);
            gload16(Ag + (size_t)row*512 + k0 + sk*8, Ab + idx*8);
        }
        // B: 64 rows x 64k = 512 granules -> 2 loads/thread
        #pragma unroll
        for (int p = 0; p < 2; p++) {
            int idx = t + p*256;
            int row = idx >> 3, sl = idx & 7;
            int sk = sl ^ (row & 7);
            gload16(Bg + (size_t)row*512 + k0 + sk*8, Bb + idx*8);
        }
        __syncthreads();
        #pragma unroll
        for (int ks = 0; ks < 4; ks++) {
            int arow = wv*32 + lr;
            bf16x8 af = *(const bf16x8*)(Ab + arow*64 + (((ks*2 + lh) ^ (arow & 7)) * 8));
            #pragma unroll
            for (int ni = 0; ni < 2; ni++) {
                int brow = ni*32 + lr;
                bf16x8 bfr = *(const bf16x8*)(Bb + brow*64 + (((ks*2 + lh) ^ (brow & 7)) * 8));
                acc[ni] = MFMA32(af, bfr, acc[ni]);
            }
        }
    }

    // C/D map: col = lr (-> n), row = (r&3) + 8*(r>>2) + 4*lh (-> o)
    #pragma unroll
    for (int q = 0; q < 4; q++) {
        int obase = o0 + wv*32 + 8*q + 4*lh;
        float4 bv = *(const float4*)(bias + obase);
        #pragma unroll
        for (int ni = 0; ni < 2; ni++) {
            int nn = n0 + ni*32 + lr;
            #pragma unroll
            for (int j = 0; j < 4; j++)
                Yout[((size_t)bb*512 + obase + j)*1024 + nn] = acc[ni][q*4+j] + bv[j];
        }
    }
}

// ---------------- MFMA flash attention (round-10 verified): 8 waves, 2-buffer, C-init m-fold ----------------
__global__ __launch_bounds__(512) void attn_mfma(const __hip_bfloat16* __restrict__ QT,
                                                 const __hip_bfloat16* __restrict__ KT,
                                                 const __hip_bfloat16* __restrict__ Vb,
                                                 __hip_bfloat16* __restrict__ valsT) {
    // XCD-grouped decomposition: all 8 q-tiles of one (b,h) share an XCD
    const int bh = ((blockIdx.x & 7) << 3) | ((blockIdx.x >> 3) & 7);
    const int qt = blockIdx.x >> 6;            // 0..7 (128 queries each)
    const int t = threadIdx.x;                 // 0..511
    const int wv = t >> 6, lane = t & 63;
    const int g = lane >> 4, li = lane & 15;

    const __hip_bfloat16* QTg = QT + (size_t)bh * NN * 64;
    const __hip_bfloat16* KTg = KT + (size_t)bh * NN * 64;
    const __hip_bfloat16* Vg  = Vb + (size_t)bh * 64 * NN;

    __shared__ __align__(16) __hip_bfloat16 k_ls[2*4096];
    __shared__ __align__(16) __hip_bfloat16 v_ls[2*4096];

    const int nq0 = qt*128 + wv*16;

    // Q fragments: pre-scaled + fragment-permuted in global
    bf16x8 qf[2];
    {
        const __hip_bfloat16* qp = QTg + (size_t)(nq0 + li) * 64;
        qf[0] = *(const bf16x8*)(qp + 8*g);
        qf[1] = *(const bf16x8*)(qp + 32 + 8*g);
    }

    // all-ones B fragment (bf16 1.0) for the l row-sum MFMA
    bf16x8 onesf;
    #pragma unroll
    for (int j = 0; j < 8; j++) onesf[j] = (short)0x3F80;

    float m_run = 0.0f;     // folded into QK^T C-operand; set to cmax at ck=0
    f32x4 o_acc[4], o_l;
    #pragma unroll
    for (int dt = 0; dt < 4; dt++) { o_acc[dt][0]=0.f; o_acc[dt][1]=0.f; o_acc[dt][2]=0.f; o_acc[dt][3]=0.f; }
    o_l[0]=0.f; o_l[1]=0.f; o_l[2]=0.f; o_l[3]=0.f;

    // one K-load + one V-load per thread per chunk (512 threads x 16B = 8KB each)
    auto STAGE = [&](int buf, int ck) {
        const int mc0 = ck * 64;
        int row = t >> 3, sl = t & 7;
        int sk = sl ^ (row & 7);
        gload16(KTg + (size_t)(mc0+row)*64 + sk*8, k_ls + buf*4096 + t*8);
        gload16(Vg + (size_t)row*NN + mc0 + sk*8, v_ls + buf*4096 + t*8);
    };

    STAGE(0, 0);
    __syncthreads();
    int cur = 0;

    for (int ck = 0; ck < 16; ck++) {
        if (ck < 15) STAGE(cur ^ 1, ck + 1);

        const __hip_bfloat16* kb = k_ls + cur*4096;
        const __hip_bfloat16* vb = v_ls + cur*4096;

        // QK^T (S^T): A=K-frag rows=keys, B=Q-frag cols=queries.
        // C-init = -m_run folds the max-subtraction into the MFMA accumulate.
        f32x4 cini;
        cini[0] = -m_run; cini[1] = -m_run; cini[2] = -m_run; cini[3] = -m_run;
        f32x4 s_acc[4];
        __builtin_amdgcn_s_setprio(1);
        #pragma unroll
        for (int mt = 0; mt < 4; mt++) {
            f32x4 c = cini;
            #pragma unroll
            for (int hf = 0; hf < 2; hf++) {
                int row = mt*16 + li;
                int sl = ((hf<<2) + g) ^ (li & 7);
                bf16x8 kf = *(const bf16x8*)(kb + row*64 + sl*8);
                c = MFMA16(kf, qf[hf], c);
            }
            s_acc[mt] = c;
        }
        __builtin_amdgcn_s_setprio(0);

        // row max (relative to m_run) via max chain, then cross-lane
        float cmax = fmaxf(s_acc[0][0], s_acc[0][1]);
        cmax = fmaxf(fmaxf(cmax, s_acc[0][2]), s_acc[0][3]);
        cmax = fmaxf(fmaxf(cmax, s_acc[1][0]), s_acc[1][1]);
        cmax = fmaxf(fmaxf(cmax, s_acc[1][2]), s_acc[1][3]);
        cmax = fmaxf(fmaxf(cmax, s_acc[2][0]), s_acc[2][1]);
        cmax = fmaxf(fmaxf(cmax, s_acc[2][2]), s_acc[2][3]);
        cmax = fmaxf(fmaxf(cmax, s_acc[3][0]), s_acc[3][1]);
        cmax = fmaxf(fmaxf(cmax, s_acc[3][2]), s_acc[3][3]);
        cmax = fmaxf(cmax, __shfl_xor(cmax, 16));
        cmax = fmaxf(cmax, __shfl_xor(cmax, 32));

        if (ck == 0) {
            // force-set running max (round-8 semantics; accumulators are zero)
            #pragma unroll
            for (int mt = 0; mt < 4; mt++) {
                s_acc[mt][0] -= cmax; s_acc[mt][1] -= cmax;
                s_acc[mt][2] -= cmax; s_acc[mt][3] -= cmax;
            }
            m_run = cmax;
        } else if (!__all(cmax <= 8.0f)) {        // defer-max (T13), THR=8 in log2
            float d = fmaxf(cmax, 0.0f);
            float resc = __builtin_amdgcn_exp2f(-d);
            f32x4 rv;
            #pragma unroll
            for (int r = 0; r < 4; r++) rv[r] = __shfl(resc, 4*g + r);
            #pragma unroll
            for (int dt = 0; dt < 4; dt++) {
                o_acc[dt][0]*=rv[0]; o_acc[dt][1]*=rv[1]; o_acc[dt][2]*=rv[2]; o_acc[dt][3]*=rv[3];
            }
            o_l[0]*=rv[0]; o_l[1]*=rv[1]; o_l[2]*=rv[2]; o_l[3]*=rv[3];
            #pragma unroll
            for (int mt = 0; mt < 4; mt++) {
                s_acc[mt][0] -= d; s_acc[mt][1] -= d;
                s_acc[mt][2] -= d; s_acc[mt][3] -= d;
            }
            m_run += d;
        }

        // P = exp2(s_acc) (already max-relative), packed via v_cvt_pk_bf16_f32
        bf16x8 pf[2];
        #pragma unroll
        for (int ks = 0; ks < 2; ks++) {
            union { bf16x8 v; unsigned u[4]; } pk;
            #pragma unroll
            for (int d4 = 0; d4 < 4; d4++) {
                const int i0 = 8*ks + 2*d4, i1 = i0 + 1;
                float e0 = __builtin_amdgcn_exp2f(s_acc[i0>>2][i0&3]);
                float e1 = __builtin_amdgcn_exp2f(s_acc[i1>>2][i1&3]);
                pk.u[d4] = cvt_pk_bf16(e0, e1);
            }
            pf[ks] = pk.v;
        }

        // PV + l row-sum: A=P rows=queries; B=V-frag cols=d' / all-ones
        __builtin_amdgcn_s_setprio(1);
        #pragma unroll
        for (int dt = 0; dt < 4; dt++) {
            #pragma unroll
            for (int ks = 0; ks < 2; ks++) {
                int row = dt*16 + li;
                int sl = ((ks<<2) + g) ^ (li & 7);
                bf16x8 vf = *(const bf16x8*)(vb + row*64 + sl*8);
                o_acc[dt] = MFMA16(pf[ks], vf, o_acc[dt]);
            }
        }
        o_l = MFMA16(pf[0], onesf, o_l);
        o_l = MFMA16(pf[1], onesf, o_l);
        __builtin_amdgcn_s_setprio(0);

        __syncthreads();   // staged data ready + everyone done reading cur
        cur ^= 1;
    }

    // epilogue: out = o_acc / o_l (row r = query nq0+4g+r, lane-local l)
    f32x4 lv;
    #pragma unroll
    for (int r = 0; r < 4; r++) lv[r] = 1.0f / o_l[r];
    const int bI = bh >> 3, hI = bh & 7;
    __hip_bfloat16* vt = valsT + (size_t)bI*1024*512 + hI*64;
    #pragma unroll
    for (int dt = 0; dt < 4; dt++)
        #pragma unroll
        for (int r = 0; r < 4; r++)
            vt[(size_t)(nq0 + 4*g + r)*512 + dt*16 + li] = __float2bfloat16(o_acc[dt][r]*lv[r]);
}

extern "C" void kernel_launch(void* const* d_in, const int* in_sizes, int n_in,
                              void* d_out, int out_size, void* d_ws, size_t ws_size,
                              hipStream_t stream) {
    const float* x      = (const float*)d_in[0];
    const float* gamma  = (const float*)d_in[1];
    const float* beta   = (const float*)d_in[2];
    const float* w_qkv  = (const float*)d_in[3];
    const float* b_qkv  = (const float*)d_in[4];
    const float* w_proj = (const float*)d_in[5];
    const float* b_proj = (const float*)d_in[6];
    float* ws   = (float*)d_ws;
    float* out  = (float*)d_out;
    __hip_bfloat16* xnT   = (__hip_bfloat16*)(ws + WS_XNT);
    __hip_bfloat16* QT    = (__hip_bfloat16*)(ws + WS_QT);
    __hip_bfloat16* KT    = (__hip_bfloat16*)(ws + WS_KT);
    __hip_bfloat16* Vx    = (__hip_bfloat16*)(ws + WS_V);
    __hip_bfloat16* valsT = (__hip_bfloat16*)(ws + WS_VALST);
    __hip_bfloat16* wqb   = (__hip_bfloat16*)(ws + WS_WQB);
    __hip_bfloat16* wpb   = (__hip_bfloat16*)(ws + WS_WPB);

    prep_kernel<<<dim3(512), dim3(256), 0, stream>>>(x, w_qkv, w_proj, ws);
    normalize_t<<<dim3(1024), dim3(256), 0, stream>>>(x, gamma, beta, ws, xnT);
    gemm_qkv<<<dim3(768), dim3(256), 0, stream>>>(wqb, xnT, b_qkv, QT, KT, Vx);
    attn_mfma<<<dim3(512), dim3(512), 0, stream>>>(QT, KT, Vx, valsT);
    gemm_proj<<<dim3(512), dim3(256), 0, stream>>>(wpb, valsT, b_proj, out);
}

// Round 16
// 69.823 us; speedup vs baseline: 1.1393x; 1.0265x over previous
//
#include <hip/hip_runtime.h>
#include <hip/hip_bf16.h>
#include <math.h>

#define NB 8
#define NC 512
#define NN 1024      // H*W
#define NHEADS 8
#define EPSV 1e-5f
#define SC2F 0.06376351307f   // 512^-0.5 * log2(e)

typedef __attribute__((ext_vector_type(8))) short bf16x8;
typedef __attribute__((ext_vector_type(4))) short bf16x4;
typedef __attribute__((ext_vector_type(4))) float f32x4;
typedef __attribute__((ext_vector_type(16))) float f32x16;

#define MFMA16(a,b,c) __builtin_amdgcn_mfma_f32_16x16x32_bf16(a,b,c,0,0,0)
#define MFMA32(a,b,c) __builtin_amdgcn_mfma_f32_32x32x16_bf16(a,b,c,0,0,0)

static __device__ __forceinline__ short f2bf(float f) {
    __hip_bfloat16 h = __float2bfloat16(f);
    return *reinterpret_cast<short*>(&h);
}

static __device__ __forceinline__ unsigned cvt_pk_bf16(float lo, float hi) {
    unsigned r;
    asm("v_cvt_pk_bf16_f32 %0, %1, %2" : "=v"(r) : "v"(lo), "v"(hi));
    return r;
}

static __device__ __forceinline__ void gload16(const void* g, void* l) {
    __builtin_amdgcn_global_load_lds((const __attribute__((address_space(1))) void*)g,
                                     (__attribute__((address_space(3))) void*)l, 16, 0, 0);
}

// ws layout (float offsets):
#define WS_PART_SUM 0            // 512
#define WS_PART_SQ  1024         // 512
#define WS_XNT   4096                    // bf16 [8][1024][512]
#define WS_QT    (WS_XNT  + 2097152)     // bf16 [64][1024][64]  (d fragment-permuted, pre-scaled)
#define WS_KT    (WS_QT   + 2097152)     // bf16 [64][1024][64]  (d fragment-permuted)
#define WS_V     (WS_KT   + 2097152)     // bf16 [64][64][1024]  (keys permuted within 64-groups)
#define WS_VALST (WS_V    + 2097152)     // bf16 [8][1024][512]
#define WS_WQB   (WS_VALST+ 2097152)     // bf16 [1536][512]
#define WS_WPB   (WS_WQB  + 393216)      // bf16 [512][512]

// ---------------- prep: batch-stat partials + weight convert (fused, 512 blocks) ----------------
__global__ __launch_bounds__(256) void prep_kernel(const float* __restrict__ x,
                                                   const float* __restrict__ wq,
                                                   const float* __restrict__ wp,
                                                   float* __restrict__ ws) {
    int blk = blockIdx.x;
    int b = blk >> 6;
    int s = blk & 63;
    const float* xb = x + (size_t)b * (NC * NN) + (size_t)s * 8192;
    float sum = 0.f, sq = 0.f;
    for (int i = threadIdx.x; i < 2048; i += 256) {
        float4 v = ((const float4*)xb)[i];
        sum += v.x + v.y + v.z + v.w;
        sq  += v.x*v.x + v.y*v.y + v.z*v.z + v.w*v.w;
    }
    #pragma unroll
    for (int off = 32; off; off >>= 1) {
        sum += __shfl_down(sum, off);
        sq  += __shfl_down(sq,  off);
    }
    __shared__ float s1[4], s2[4];
    int wave = threadIdx.x >> 6, lane = threadIdx.x & 63;
    if (lane == 0) { s1[wave] = sum; s2[wave] = sq; }

    // weight convert: 2 float4 per thread, 512*256*2 = 262144 = exact cover
    #pragma unroll
    for (int r = 0; r < 2; r++) {
        int i = blk * 512 + threadIdx.x * 2 + r;
        const float* src;
        __hip_bfloat16* d;
        if (i < 196608) { src = wq; d = (__hip_bfloat16*)(ws + WS_WQB); }
        else            { src = wp; d = (__hip_bfloat16*)(ws + WS_WPB); i -= 196608; }
        float4 v = ((const float4*)src)[i];
        bf16x4 w;
        w[0] = f2bf(v.x); w[1] = f2bf(v.y); w[2] = f2bf(v.z); w[3] = f2bf(v.w);
        *(bf16x4*)(d + (size_t)i*4) = w;
    }

    __syncthreads();
    if (threadIdx.x == 0) {
        float a = 0.f, c2 = 0.f;
        #pragma unroll
        for (int w = 0; w < 4; w++) { a += s1[w]; c2 += s2[w]; }
        ws[WS_PART_SUM + b*64 + s] = a;
        ws[WS_PART_SQ  + b*64 + s] = c2;
    }
}

// ---------------- normalize + transpose -> xnT[b][n][c] bf16 (stats finalized inline) ----------------
__global__ __launch_bounds__(256) void normalize_t(const float* __restrict__ x,
                                                   const float* __restrict__ gamma,
                                                   const float* __restrict__ beta,
                                                   const float* __restrict__ ws,
                                                   __hip_bfloat16* __restrict__ xnT) {
    int nt = blockIdx.x & 15, ct = (blockIdx.x >> 4) & 7, b = blockIdx.x >> 7;
    __shared__ __hip_bfloat16 tb[64][72];
    float s = 0.f, q = 0.f;
    const float4* ps = (const float4*)(ws + WS_PART_SUM + b*64);
    const float4* pq = (const float4*)(ws + WS_PART_SQ  + b*64);
    #pragma unroll
    for (int i = 0; i < 16; i++) {
        float4 a = ps[i]; s += a.x + a.y + a.z + a.w;
        float4 c = pq[i]; q += c.x + c.y + c.z + c.w;
    }
    const float inv = 1.f / (float)(NC * NN);
    float mu   = s * inv;
    float var  = q * inv - mu * mu;
    float rstd = rsqrtf(var + EPSV);

    const float* xb = x + ((size_t)b*512 + ct*64)*1024 + nt*64;
    int t = threadIdx.x;
    int cl = t >> 4, n4 = (t & 15) * 4;
    #pragma unroll
    for (int i = 0; i < 4; i++) {
        int c = i*16 + cl;
        float gm = gamma[ct*64 + c];
        float g = gm * rstd;
        float be = beta[ct*64 + c] - mu * g;
        float4 v = *(const float4*)(xb + (size_t)c*1024 + n4);
        tb[n4+0][c] = __float2bfloat16(v.x*g + be);
        tb[n4+1][c] = __float2bfloat16(v.y*g + be);
        tb[n4+2][c] = __float2bfloat16(v.z*g + be);
        tb[n4+3][c] = __float2bfloat16(v.w*g + be);
    }
    __syncthreads();
    #pragma unroll
    for (int i = 0; i < 2; i++) {
        int idx = i*256 + t;
        int n = idx >> 3, c8 = (idx & 7) * 8;
        *(bf16x8*)(xnT + ((size_t)b*1024 + nt*64 + n)*512 + ct*64 + c8) =
            *(const bf16x8*)&tb[n][c8];
    }
}

// ---------------- QKV GEMM: 128o x 64n tiles -> 1536 blocks (6 blocks/CU) ----------------
// Wave wv owns rows o0+wv*32, both 32-col halves. Same K-accumulation order as before
// (bit-identical numerics); epilogue re-derived for the 64-wide tile.
__global__ __launch_bounds__(256) void gemm_qkv(const __hip_bfloat16* __restrict__ Aw,
                                                const __hip_bfloat16* __restrict__ Bx,
                                                const float* __restrict__ bias,
                                                __hip_bfloat16* __restrict__ QTx,
                                                __hip_bfloat16* __restrict__ KTx,
                                                __hip_bfloat16* __restrict__ Vx) {
    __shared__ __align__(16) __hip_bfloat16 lds_raw[12288];  // A 128x64 (16KB) + B 64x64 (8KB); tb overlay 17.4KB
    const int bx = blockIdx.x;
    const int swz = (bx & 7) * 192 + (bx >> 3);   // batch-affinity XCD swizzle (1536%8==0)
    const int nt = swz & 15;
    const int ot = (swz >> 4) % 12;
    const int bb = swz / 192;
    const int o0 = ot * 128, n0 = nt * 64;

    const int t = threadIdx.x, wv = t >> 6, l = t & 63;
    const int lr = l & 31, lh = l >> 5;

    const __hip_bfloat16* Ag = Aw + (size_t)o0 * 512;
    const __hip_bfloat16* Bg = Bx + ((size_t)bb * 1024 + n0) * 512;
    __hip_bfloat16* Ab = lds_raw;          // [128][64], XOR-swizzled granules
    __hip_bfloat16* Bb = lds_raw + 128*64; // [64][64]

    f32x16 acc[2];
    #pragma unroll
    for (int ni = 0; ni < 2; ni++)
        #pragma unroll
        for (int r = 0; r < 16; r++) acc[ni][r] = 0.f;

    for (int k0 = 0; k0 < 512; k0 += 64) {
        __syncthreads();
        // A: 128 rows x 64k = 1024 granules of 16B -> 4 loads/thread
        #pragma unroll
        for (int p = 0; p < 4; p++) {
            int idx = t + p*256;
            int row = idx >> 3, sl = idx & 7;
            int sk = sl ^ (row & 7);
            gload16(Ag + (size_t)row*512 + k0 + sk*8, Ab + idx*8);
        }
        // B: 64 rows x 64k = 512 granules -> 2 loads/thread
        #pragma unroll
        for (int p = 0; p < 2; p++) {
            int idx = t + p*256;
            int row = idx >> 3, sl = idx & 7;
            int sk = sl ^ (row & 7);
            gload16(Bg + (size_t)row*512 + k0 + sk*8, Bb + idx*8);
        }
        __syncthreads();
        #pragma unroll
        for (int ks = 0; ks < 4; ks++) {
            int arow = wv*32 + lr;
            bf16x8 af = *(const bf16x8*)(Ab + arow*64 + (((ks*2 + lh) ^ (arow & 7)) * 8));
            #pragma unroll
            for (int ni = 0; ni < 2; ni++) {
                int brow = ni*32 + lr;
                bf16x8 bfr = *(const bf16x8*)(Bb + brow*64 + (((ks*2 + lh) ^ (brow & 7)) * 8));
                acc[ni] = MFMA32(af, bfr, acc[ni]);
            }
        }
    }

    // C/D map (verified m74/m101): col = lr (-> n), row = (r&3) + 8*(r>>2) + 4*lh (-> o within wave block)
    int sec = o0 >> 9;                 // 0=Q 1=K 2=V
    if (sec == 2) {
        int od0 = o0 & 511;
        // permute keys within 64-groups: m=32ks+16u+4g+j -> p=32ks+8g+4u+j
        int mperm = ((lr & 12) << 1) + ((lr & 16) >> 2) + (lr & 3);
        #pragma unroll
        for (int q = 0; q < 4; q++) {
            int ob = wv*32 + 8*q + 4*lh;
            float4 bv = *(const float4*)(bias + o0 + ob);
            #pragma unroll
            for (int j = 0; j < 4; j++) {
                int ol = od0 + ob + j;
                int h = ol >> 6, d = ol & 63;
                __hip_bfloat16* dst = Vx + ((size_t)((bb<<3) + h)*64 + d)*1024;
                #pragma unroll
                for (int ni = 0; ni < 2; ni++) {
                    int nn = n0 + ni*32 + mperm;
                    dst[nn] = __float2bfloat16(acc[ni][q*4+j] + bv[j]);
                }
            }
        }
    } else {
        // Q gets pre-scaled by 512^-0.5*log2(e) so attention skips the scale mul
        const float qs = (sec == 0) ? SC2F : 1.0f;
        __syncthreads();
        __hip_bfloat16* tb = lds_raw;  // [64][136]
        #pragma unroll
        for (int q = 0; q < 4; q++) {
            int ob = wv*32 + 8*q + 4*lh;
            float4 bv = *(const float4*)(bias + o0 + ob);
            #pragma unroll
            for (int ni = 0; ni < 2; ni++) {
                int nn = ni*32 + lr;
                bf16x4 w;
                #pragma unroll
                for (int j = 0; j < 4; j++) w[j] = f2bf((acc[ni][q*4+j] + bv[j]) * qs);
                *(bf16x4*)&tb[(size_t)nn*136 + ob] = w;
            }
        }
        __syncthreads();
        __hip_bfloat16* dst0 = (sec == 0) ? QTx : KTx;
        int h0 = (o0 & 511) >> 6;     // even; tile covers heads h0, h0+1
        // d-permuted store: position-group slot holds logical d {32hf+4g+j, 32hf+16+4g+j}
        #pragma unroll
        for (int i = 0; i < 4; i++) {
            int idx = i*256 + t;        // 0..1023 = 64n x 16 (hh,slot)
            int n = idx >> 4, rem = idx & 15;
            int hh = rem >> 3, slot = rem & 7;
            int hf32 = (slot & 4) << 3;
            int g4   = (slot & 3) << 2;
            bf16x4 lo = *(const bf16x4*)&tb[(size_t)n*136 + hh*64 + hf32 + g4];
            bf16x4 hi = *(const bf16x4*)&tb[(size_t)n*136 + hh*64 + hf32 + 16 + g4];
            bf16x8 w;
            w[0]=lo[0]; w[1]=lo[1]; w[2]=lo[2]; w[3]=lo[3];
            w[4]=hi[0]; w[5]=hi[1]; w[6]=hi[2]; w[7]=hi[3];
            *(bf16x8*)(dst0 + ((size_t)((bb<<3) + h0 + hh)*1024 + n0 + n)*64 + slot*8) = w;
        }
    }
}

// ---------------- proj GEMM: 128o x 64n tiles -> 512 blocks (2 blocks/CU) ----------------
__global__ __launch_bounds__(256) void gemm_proj(const __hip_bfloat16* __restrict__ Aw,
                                                 const __hip_bfloat16* __restrict__ Bx,
                                                 const float* __restrict__ bias,
                                                 float* __restrict__ Yout) {
    __shared__ __align__(16) __hip_bfloat16 lds_raw[12288];  // A 128x64 (16KB) + B 64x64 (8KB)
    const int bx = blockIdx.x;
    const int swz = (bx & 7) * 64 + (bx >> 3);   // batch-affinity XCD swizzle (512%8==0)
    const int nt = swz & 15;
    const int ot = (swz >> 4) & 3;
    const int bb = swz >> 6;
    const int o0 = ot * 128, n0 = nt * 64;

    const int t = threadIdx.x, wv = t >> 6, l = t & 63;
    const int lr = l & 31, lh = l >> 5;

    const __hip_bfloat16* Ag = Aw + (size_t)o0 * 512;
    const __hip_bfloat16* Bg = Bx + ((size_t)bb * 1024 + n0) * 512;
    __hip_bfloat16* Ab = lds_raw;          // [128][64], XOR-swizzled granules
    __hip_bfloat16* Bb = lds_raw + 128*64; // [64][64]

    f32x16 acc[2];
    #pragma unroll
    for (int ni = 0; ni < 2; ni++)
        #pragma unroll
        for (int r = 0; r < 16; r++) acc[ni][r] = 0.f;

    for (int k0 = 0; k0 < 512; k0 += 64) {
        __syncthreads();
        #pragma unroll
        for (int p = 0; p < 4; p++) {
            int idx = t + p*256;
            int row = idx >> 3, sl = idx & 7;
            int sk = sl ^ (row & 7);
            gload16(Ag + (size_t)row*512 + k0 + sk*8, Ab + idx*8);
        }
        #pragma unroll
        for (int p = 0; p < 2; p++) {
            int idx = t + p*256;
            int row = idx >> 3, sl = idx & 7;
            int sk = sl ^ (row & 7);
            gload16(Bg + (size_t)row*512 + k0 + sk*8, Bb + idx*8);
        }
        __syncthreads();
        #pragma unroll
        for (int ks = 0; ks < 4; ks++) {
            int arow = wv*32 + lr;
            bf16x8 af = *(const bf16x8*)(Ab + arow*64 + (((ks*2 + lh) ^ (arow & 7)) * 8));
            #pragma unroll
            for (int ni = 0; ni < 2; ni++) {
                int brow = ni*32 + lr;
                bf16x8 bfr = *(const bf16x8*)(Bb + brow*64 + (((ks*2 + lh) ^ (brow & 7)) * 8));
                acc[ni] = MFMA32(af, bfr, acc[ni]);
            }
        }
    }

    // C/D map: col = lr (-> n), row = (r&3) + 8*(r>>2) + 4*lh (-> o)
    #pragma unroll
    for (int q = 0; q < 4; q++) {
        int obase = o0 + wv*32 + 8*q + 4*lh;
        float4 bv = *(const float4*)(bias + obase);
        #pragma unroll
        for (int ni = 0; ni < 2; ni++) {
            int nn = n0 + ni*32 + lr;
            #pragma unroll
            for (int j = 0; j < 4; j++)
                Yout[((size_t)bb*512 + obase + j)*1024 + nn] = acc[ni][q*4+j] + bv[j];
        }
    }
}

// ---------------- MFMA flash attention (round-10 verified): 8 waves, 2-buffer, C-init m-fold ----------------
__global__ __launch_bounds__(512) void attn_mfma(const __hip_bfloat16* __restrict__ QT,
                                                 const __hip_bfloat16* __restrict__ KT,
                                                 const __hip_bfloat16* __restrict__ Vb,
                                                 __hip_bfloat16* __restrict__ valsT) {
    // XCD-grouped decomposition: all 8 q-tiles of one (b,h) share an XCD
    const int bh = ((blockIdx.x & 7) << 3) | ((blockIdx.x >> 3) & 7);
    const int qt = blockIdx.x >> 6;            // 0..7 (128 queries each)
    const int t = threadIdx.x;                 // 0..511
    const int wv = t >> 6, lane = t & 63;
    const int g = lane >> 4, li = lane & 15;

    const __hip_bfloat16* QTg = QT + (size_t)bh * NN * 64;
    const __hip_bfloat16* KTg = KT + (size_t)bh * NN * 64;
    const __hip_bfloat16* Vg  = Vb + (size_t)bh * 64 * NN;

    __shared__ __align__(16) __hip_bfloat16 k_ls[2*4096];
    __shared__ __align__(16) __hip_bfloat16 v_ls[2*4096];

    const int nq0 = qt*128 + wv*16;

    // Q fragments: pre-scaled + fragment-permuted in global
    bf16x8 qf[2];
    {
        const __hip_bfloat16* qp = QTg + (size_t)(nq0 + li) * 64;
        qf[0] = *(const bf16x8*)(qp + 8*g);
        qf[1] = *(const bf16x8*)(qp + 32 + 8*g);
    }

    // all-ones B fragment (bf16 1.0) for the l row-sum MFMA
    bf16x8 onesf;
    #pragma unroll
    for (int j = 0; j < 8; j++) onesf[j] = (short)0x3F80;

    float m_run = 0.0f;     // folded into QK^T C-operand; set to cmax at ck=0
    f32x4 o_acc[4], o_l;
    #pragma unroll
    for (int dt = 0; dt < 4; dt++) { o_acc[dt][0]=0.f; o_acc[dt][1]=0.f; o_acc[dt][2]=0.f; o_acc[dt][3]=0.f; }
    o_l[0]=0.f; o_l[1]=0.f; o_l[2]=0.f; o_l[3]=0.f;

    // one K-load + one V-load per thread per chunk (512 threads x 16B = 8KB each)
    auto STAGE = [&](int buf, int ck) {
        const int mc0 = ck * 64;
        int row = t >> 3, sl = t & 7;
        int sk = sl ^ (row & 7);
        gload16(KTg + (size_t)(mc0+row)*64 + sk*8, k_ls + buf*4096 + t*8);
        gload16(Vg + (size_t)row*NN + mc0 + sk*8, v_ls + buf*4096 + t*8);
    };

    STAGE(0, 0);
    __syncthreads();
    int cur = 0;

    for (int ck = 0; ck < 16; ck++) {
        if (ck < 15) STAGE(cur ^ 1, ck + 1);

        const __hip_bfloat16* kb = k_ls + cur*4096;
        const __hip_bfloat16* vb = v_ls + cur*4096;

        // QK^T (S^T): A=K-frag rows=keys, B=Q-frag cols=queries.
        // C-init = -m_run folds the max-subtraction into the MFMA accumulate.
        f32x4 cini;
        cini[0] = -m_run; cini[1] = -m_run; cini[2] = -m_run; cini[3] = -m_run;
        f32x4 s_acc[4];
        __builtin_amdgcn_s_setprio(1);
        #pragma unroll
        for (int mt = 0; mt < 4; mt++) {
            f32x4 c = cini;
            #pragma unroll
            for (int hf = 0; hf < 2; hf++) {
                int row = mt*16 + li;
                int sl = ((hf<<2) + g) ^ (li & 7);
                bf16x8 kf = *(const bf16x8*)(kb + row*64 + sl*8);
                c = MFMA16(kf, qf[hf], c);
            }
            s_acc[mt] = c;
        }
        __builtin_amdgcn_s_setprio(0);

        // row max (relative to m_run) via max chain, then cross-lane
        float cmax = fmaxf(s_acc[0][0], s_acc[0][1]);
        cmax = fmaxf(fmaxf(cmax, s_acc[0][2]), s_acc[0][3]);
        cmax = fmaxf(fmaxf(cmax, s_acc[1][0]), s_acc[1][1]);
        cmax = fmaxf(fmaxf(cmax, s_acc[1][2]), s_acc[1][3]);
        cmax = fmaxf(fmaxf(cmax, s_acc[2][0]), s_acc[2][1]);
        cmax = fmaxf(fmaxf(cmax, s_acc[2][2]), s_acc[2][3]);
        cmax = fmaxf(fmaxf(cmax, s_acc[3][0]), s_acc[3][1]);
        cmax = fmaxf(fmaxf(cmax, s_acc[3][2]), s_acc[3][3]);
        cmax = fmaxf(cmax, __shfl_xor(cmax, 16));
        cmax = fmaxf(cmax, __shfl_xor(cmax, 32));

        if (ck == 0) {
            // force-set running max (round-8 semantics; accumulators are zero)
            #pragma unroll
            for (int mt = 0; mt < 4; mt++) {
                s_acc[mt][0] -= cmax; s_acc[mt][1] -= cmax;
                s_acc[mt][2] -= cmax; s_acc[mt][3] -= cmax;
            }
            m_run = cmax;
        } else if (!__all(cmax <= 8.0f)) {        // defer-max (T13), THR=8 in log2
            float d = fmaxf(cmax, 0.0f);
            float resc = __builtin_amdgcn_exp2f(-d);
            f32x4 rv;
            #pragma unroll
            for (int r = 0; r < 4; r++) rv[r] = __shfl(resc, 4*g + r);
            #pragma unroll
            for (int dt = 0; dt < 4; dt++) {
                o_acc[dt][0]*=rv[0]; o_acc[dt][1]*=rv[1]; o_acc[dt][2]*=rv[2]; o_acc[dt][3]*=rv[3];
            }
            o_l[0]*=rv[0]; o_l[1]*=rv[1]; o_l[2]*=rv[2]; o_l[3]*=rv[3];
            #pragma unroll
            for (int mt = 0; mt < 4; mt++) {
                s_acc[mt][0] -= d; s_acc[mt][1] -= d;
                s_acc[mt][2] -= d; s_acc[mt][3] -= d;
            }
            m_run += d;
        }

        // P = exp2(s_acc) (already max-relative), packed via v_cvt_pk_bf16_f32
        bf16x8 pf[2];
        #pragma unroll
        for (int ks = 0; ks < 2; ks++) {
            union { bf16x8 v; unsigned u[4]; } pk;
            #pragma unroll
            for (int d4 = 0; d4 < 4; d4++) {
                const int i0 = 8*ks + 2*d4, i1 = i0 + 1;
                float e0 = __builtin_amdgcn_exp2f(s_acc[i0>>2][i0&3]);
                float e1 = __builtin_amdgcn_exp2f(s_acc[i1>>2][i1&3]);
                pk.u[d4] = cvt_pk_bf16(e0, e1);
            }
            pf[ks] = pk.v;
        }

        // PV + l row-sum: A=P rows=queries; B=V-frag cols=d' / all-ones
        __builtin_amdgcn_s_setprio(1);
        #pragma unroll
        for (int dt = 0; dt < 4; dt++) {
            #pragma unroll
            for (int ks = 0; ks < 2; ks++) {
                int row = dt*16 + li;
                int sl = ((ks<<2) + g) ^ (li & 7);
                bf16x8 vf = *(const bf16x8*)(vb + row*64 + sl*8);
                o_acc[dt] = MFMA16(pf[ks], vf, o_acc[dt]);
            }
        }
        o_l = MFMA16(pf[0], onesf, o_l);
        o_l = MFMA16(pf[1], onesf, o_l);
        __builtin_amdgcn_s_setprio(0);

        __syncthreads();   // staged data ready + everyone done reading cur
        cur ^= 1;
    }

    // epilogue: out = o_acc / o_l (row r = query nq0+4g+r, lane-local l)
    f32x4 lv;
    #pragma unroll
    for (int r = 0; r < 4; r++) lv[r] = 1.0f / o_l[r];
    const int bI = bh >> 3, hI = bh & 7;
    __hip_bfloat16* vt = valsT + (size_t)bI*1024*512 + hI*64;
    #pragma unroll
    for (int dt = 0; dt < 4; dt++)
        #pragma unroll
        for (int r = 0; r < 4; r++)
            vt[(size_t)(nq0 + 4*g + r)*512 + dt*16 + li] = __float2bfloat16(o_acc[dt][r]*lv[r]);
}

extern "C" void kernel_launch(void* const* d_in, const int* in_sizes, int n_in,
                              void* d_out, int out_size, void* d_ws, size_t ws_size,
                              hipStream_t stream) {
    const float* x      = (const float*)d_in[0];
    const float* gamma  = (const float*)d_in[1];
    const float* beta   = (const float*)d_in[2];
    const float* w_qkv  = (const float*)d_in[3];
    const float* b_qkv  = (const float*)d_in[4];
    const float* w_proj = (const float*)d_in[5];
    const float* b_proj = (const float*)d_in[6];
    float* ws   = (float*)d_ws;
    float* out  = (float*)d_out;
    __hip_bfloat16* xnT   = (__hip_bfloat16*)(ws + WS_XNT);
    __hip_bfloat16* QT    = (__hip_bfloat16*)(ws + WS_QT);
    __hip_bfloat16* KT    = (__hip_bfloat16*)(ws + WS_KT);
    __hip_bfloat16* Vx    = (__hip_bfloat16*)(ws + WS_V);
    __hip_bfloat16* valsT = (__hip_bfloat16*)(ws + WS_VALST);
    __hip_bfloat16* wqb   = (__hip_bfloat16*)(ws + WS_WQB);
    __hip_bfloat16* wpb   = (__hip_bfloat16*)(ws + WS_WPB);

    prep_kernel<<<dim3(512), dim3(256), 0, stream>>>(x, w_qkv, w_proj, ws);
    normalize_t<<<dim3(1024), dim3(256), 0, stream>>>(x, gamma, beta, ws, xnT);
    gemm_qkv<<<dim3(1536), dim3(256), 0, stream>>>(wqb, xnT, b_qkv, QT, KT, Vx);
    attn_mfma<<<dim3(512), dim3(512), 0, stream>>>(QT, KT, Vx, valsT);
    gemm_proj<<<dim3(512), dim3(256), 0, stream>>>(wpb, valsT, b_proj, out);
}